// Round 15
// baseline (940.740 us; speedup 1.0000x reference)
//
#include <hip/hip_runtime.h>
#include <hip/hip_bf16.h>
#include <math.h>

// Fused CBAM + deformable-conv pipeline. R15: dcn goes 512-thread / 8-wave
// (4 channels per wave, was 8): LDS 64.5KB -> 2 blocks/CU = 16 waves/CU
// (50% occ vs 34%), halved per-wave latency chains. Two-stage LDS reduction.
// Everything else identical to R14 (best: 854us total, dcn 490us).

constexpr int B = 4, N = 64, F = 32;
constexpr int H = 192, W = 192, HW = H * W;
constexpr int H2 = 96, W2 = 96, HW2 = H2 * W2;
constexpr int OMP = 1024;  // padded per-pixel channel stride for om2r
constexpr int OMS = 64;    // s_omw per-channel stride

using u32 = unsigned int;
using f16x8 = __attribute__((ext_vector_type(8))) _Float16;
using f32x4 = __attribute__((ext_vector_type(4))) float;

__device__ __forceinline__ float sigmoidf_(float v) {
  return 1.f / (1.f + expf(-v));
}
__device__ __forceinline__ f16x8 bc_(uint4 u) {
  union { uint4 u; f16x8 h; } x; x.u = u; return x.h;
}
__device__ __forceinline__ u32 pk_(float a, float b) {
  union { u32 u; _Float16 h[2]; } x; x.h[0] = (_Float16)a; x.h[1] = (_Float16)b;
  return x.u;
}

// ---- diagnostic fill ----
__global__ __launch_bounds__(256) void dsta_fill(float* __restrict__ out,
                                                 int n, float v) {
  int i = blockIdx.x * 256 + threadIdx.x;
  if (i < n) out[i] = v;
}

// ---- channel mean & max maps -> stats(B,2,H,W) ----
__global__ __launch_bounds__(256) void dsta_stats(
    const float* __restrict__ x2, float* __restrict__ stats) {
  int idx = blockIdx.x * 256 + threadIdx.x;
  int p = idx % HW, b = idx / HW;
  float s = 0.f, m = -3.4e38f;
  for (int c = 0; c < F; ++c) {
    float v = x2[((size_t)(b * F + c)) * HW + p];
    s += v; m = fmaxf(m, v);
  }
  stats[((size_t)(b * 2 + 0)) * HW + p] = s * (1.f / F);
  stats[((size_t)(b * 2 + 1)) * HW + p] = m;
}

// ---- per-(b,c) spatial mean & max ----
__global__ __launch_bounds__(256) void dsta_ca_red(
    const float* __restrict__ x2, float* __restrict__ ap, float* __restrict__ mp) {
  __shared__ float ss[256], sm[256];
  int bc = blockIdx.x;
  const float* src = x2 + (size_t)bc * HW;
  float s = 0.f, m = -3.4e38f;
  for (int i = threadIdx.x; i < HW; i += 256) {
    float v = src[i]; s += v; m = fmaxf(m, v);
  }
  ss[threadIdx.x] = s; sm[threadIdx.x] = m;
  __syncthreads();
  for (int o = 128; o > 0; o >>= 1) {
    if (threadIdx.x < o) {
      ss[threadIdx.x] += ss[threadIdx.x + o];
      sm[threadIdx.x] = fmaxf(sm[threadIdx.x], sm[threadIdx.x + o]);
    }
    __syncthreads();
  }
  if (threadIdx.x == 0) { ap[bc] = ss[0] * (1.f / HW); mp[bc] = sm[0]; }
}

// ---- channel-attention MLP ----
__global__ __launch_bounds__(128) void dsta_ca_mlp(
    const float* __restrict__ ap, const float* __restrict__ mp,
    const float* __restrict__ w1, const float* __restrict__ w2,
    float* __restrict__ sig) {
  int t = threadIdx.x;
  if (t >= B * F) return;
  int b = t / F, co = t % F;
  float accA = 0.f, accB = 0.f;
  for (int j = 0; j < F / 2; ++j) {
    float hA = 0.f, hB = 0.f;
    for (int c = 0; c < F; ++c) {
      float wv = w1[j * F + c];
      hA = fmaf(wv, ap[b * F + c], hA);
      hB = fmaf(wv, mp[b * F + c], hB);
    }
    hA = fmaxf(hA, 0.f); hB = fmaxf(hB, 0.f);
    float wv2 = w2[co * (F / 2) + j];
    accA = fmaf(wv2, hA, accA);
    accB = fmaf(wv2, hB, accB);
  }
  sig[t] = sigmoidf_(accA + accB);
}

// ---- fused spatial-attention (7x7 conv + silu) + channel-att + 1x1 fuse ----
__global__ __launch_bounds__(256) void dsta_safuse(
    const float* __restrict__ stats, const float* __restrict__ x2,
    const float* __restrict__ sig, const float* __restrict__ sa_w,
    const float* __restrict__ fw, const float* __restrict__ fb,
    float* __restrict__ x2f) {
  int idx = blockIdx.x * 256 + threadIdx.x;   // B*HW
  int p = idx % HW, b = idx / HW;
  int h = p / W, w = p % W;
  float acc[F];
#pragma unroll
  for (int j = 0; j < F; ++j) acc[j] = 0.f;   // sa has no bias
#pragma unroll 1
  for (int ci = 0; ci < 2; ++ci) {
    const float* sp = stats + ((size_t)(b * 2 + ci)) * HW;
#pragma unroll 1
    for (int ky = 0; ky < 7; ++ky) {
      int yy = h + ky - 3;
      float tap[7];
#pragma unroll
      for (int kx = 0; kx < 7; ++kx) {
        int xx = w + kx - 3;
        tap[kx] = (yy >= 0 && yy < H && xx >= 0 && xx < W) ? sp[yy * W + xx] : 0.f;
      }
#pragma unroll
      for (int j = 0; j < F; ++j) {
        const float* wp = sa_w + ((size_t)(j * 2 + ci) * 49) + ky * 7;
#pragma unroll
        for (int kx = 0; kx < 7; ++kx) acc[j] = fmaf(wp[kx], tap[kx], acc[j]);
      }
    }
  }
  float accf[F];
#pragma unroll
  for (int o = 0; o < F; ++o) accf[o] = fb[o];
#pragma unroll 1
  for (int j = 0; j < F; ++j) {
    float v = acc[j];
    float asv = sigmoidf_(v) * v;
#pragma unroll
    for (int o = 0; o < F; ++o) accf[o] = fmaf(fw[o * 2 * F + j], asv, accf[o]);
  }
#pragma unroll 1
  for (int c = 0; c < F; ++c) {
    float xc = sig[b * F + c] * x2[((size_t)(b * F + c)) * HW + p];
#pragma unroll
    for (int o = 0; o < F; ++o)
      accf[o] = fmaf(fw[o * 2 * F + F + c], xc, accf[o]);
  }
#pragma unroll
  for (int o = 0; o < F; ++o)
    x2f[((size_t)(b * F + o)) * HW + p] = fmaxf(accf[o], 0.f);
}

// ---- down: 3x3 s2 p1 conv 32->32 + relu ----
__global__ __launch_bounds__(256) void dsta_down(
    const float* __restrict__ x2f, const float* __restrict__ wgt,
    const float* __restrict__ bias, float* __restrict__ x3) {
  int idx = blockIdx.x * 256 + threadIdx.x;
  int p = idx % HW2; int r = idx / HW2;
  int g = r % 4, b = r / 4;
  int h2 = p / W2, w2 = p % W2;
  float acc[8];
#pragma unroll
  for (int j = 0; j < 8; ++j) acc[j] = bias[g * 8 + j];
  for (int ci = 0; ci < F; ++ci) {
    const float* xp = x2f + ((size_t)(b * F + ci)) * HW;
    float tap[9];
#pragma unroll
    for (int t = 0; t < 9; ++t) {
      int yy = 2 * h2 + t / 3 - 1, xx = 2 * w2 + t % 3 - 1;
      tap[t] = (yy >= 0 && yy < H && xx >= 0 && xx < W) ? xp[yy * W + xx] : 0.f;
    }
#pragma unroll
    for (int j = 0; j < 8; ++j) {
      const float* wp = wgt + ((size_t)(g * 8 + j) * F + ci) * 9;
#pragma unroll
      for (int t = 0; t < 9; ++t) acc[j] = fmaf(wp[t], tap[t], acc[j]);
    }
  }
#pragma unroll
  for (int j = 0; j < 8; ++j)
    x3[((size_t)(b * F + g * 8 + j)) * HW2 + p] = fmaxf(acc[j], 0.f);
}

// ---- weight frag-pack (fp16 pairs), same k-map as im2col builder ----
__global__ __launch_bounds__(256) void dsta_pack(
    const float* __restrict__ mw, const float* __restrict__ m2w,
    const float* __restrict__ c1w, const float* __restrict__ ow,
    u32* __restrict__ pw1, u32* __restrict__ pw2,
    u32* __restrict__ pc1, u32* __restrict__ pco) {
  int i = blockIdx.x * 256 + threadIdx.x;   // 290,304 total
  int r = i & 3, l = (i >> 2) & 63;
  int k0 = 8 * (l >> 4) + 2 * r;            // base within kt tile
  if (i < 147456) {
    int kt = (i >> 8) % 9, q = (i >> 8) / 9;
    int mt = q & 1, c = q >> 1;
    int ochl = mt * 16 + (l & 15);
    int kk = kt * 32 + k0;
    float v0 = 0.f, v1 = 0.f;
    if (ochl < 27) {
      int ochg = ochl < 18 ? c * 18 + ochl : 576 + c * 9 + (ochl - 18);
      v0 = mw[(size_t)ochg * 288 + kk];
      v1 = mw[(size_t)ochg * 288 + kk + 1];
    }
    pw1[i] = pk_(v0, v1);
  } else if (i < 271872) {
    int i2 = i - 147456;
    int kt = (i2 >> 8) % 9, mt = (i2 >> 8) / 9;
    int och = mt * 16 + (l & 15);
    int kk = kt * 32 + k0;
    pw2[i2] = pk_(m2w[(size_t)och * 288 + kk], m2w[(size_t)och * 288 + kk + 1]);
  } else if (i < 281088) {
    int i3 = i - 271872;
    int kt = (i3 >> 8) % 9, q = (i3 >> 8) / 9;
    int mt = q & 1, half = q >> 1;
    int och = mt * 16 + (l & 15);             // < 32
    int kk = half * 288 + kt * 32 + k0;       // global k into 576
    pc1[i3] = pk_(c1w[(size_t)och * 576 + kk], c1w[(size_t)och * 576 + kk + 1]);
  } else {
    int i4 = i - 281088;
    int kt = (i4 >> 8) % 9, mt = (i4 >> 8) / 9;  // mt 0..3
    int och = mt * 16 + (l & 15);             // < 64
    int kk = kt * 32 + k0;
    pco[i4] = pk_(ow[(size_t)och * 288 + kk], ow[(size_t)och * 288 + kk + 1]);
  }
}

// ---- cooperative im2col builder (NT = block threads) ----
template <int SH, int SW, int NT>
__device__ __forceinline__ void build_im2col(
    const float* __restrict__ src, int y0t, int x0t,
    float* __restrict__ patch, u32* __restrict__ im2, int tid) {
  for (int i = tid; i < F * 100; i += NT) {
    int ci = i / 100, rr = i % 100;
    int yy = y0t + rr / 10 - 1, xx = x0t + rr % 10 - 1;
    patch[i] = (yy >= 0 && yy < SH && xx >= 0 && xx < SW)
                   ? src[(size_t)ci * (SH * SW) + yy * SW + xx] : 0.f;
  }
  __syncthreads();
  for (int i = tid; i < 9216; i += NT) {
    int r = i & 3, l = (i >> 2) & 63;
    int kt = (i >> 8) % 9, nt = (i >> 8) / 9;
    int j = nt * 16 + (l & 15);
    int ly = j >> 3, lx = j & 7;
    int k0 = kt * 32 + 8 * (l >> 4) + 2 * r;
    int ci0 = k0 / 9, t0 = k0 - 9 * ci0;
    int k1 = k0 + 1;
    int ci1 = k1 / 9, t1 = k1 - 9 * ci1;
    float v0 = patch[ci0 * 100 + (ly + t0 / 3) * 10 + (lx + t0 % 3)];
    float v1 = patch[ci1 * 100 + (ly + t1 / 3) * 10 + (lx + t1 % 3)];
    im2[i] = pk_(v0, v1);
  }
  __syncthreads();
}

// ---- conv1 via MFMA: 3x3 p1 conv 64->32 + bias + relu (two K-halves) ----
__global__ __launch_bounds__(256) void dsta_conv1_m(
    const float* __restrict__ x, const uint4* __restrict__ pc1,
    const float* __restrict__ bias, float* __restrict__ x2) {
  __shared__ float s_patch[F * 100];
  __shared__ uint4 s_col[2304];
  int bid = blockIdx.x;                 // B*576
  int tile = bid % 576, b = bid / 576;
  int y0t = (tile / 24) * 8, x0t = (tile % 24) * 8;
  int tid = threadIdx.x;
  int w = tid >> 6, l = tid & 63;
  int lg = l >> 4, li = l & 15;
  int mt = w & 1;
  int nt0 = w >> 1, nt1 = 2 + (w >> 1);
  f32x4 acc0 = {0.f, 0.f, 0.f, 0.f}, acc1 = {0.f, 0.f, 0.f, 0.f};
#pragma unroll 1
  for (int half = 0; half < 2; ++half) {
    build_im2col<H, W, 256>(x + ((size_t)(b * N + half * F)) * HW, y0t, x0t,
                            s_patch, (u32*)s_col, tid);
#pragma unroll 1
    for (int kt = 0; kt < 9; ++kt) {
      uint4 wf = pc1[(((half * 2 + mt) * 9) + kt) * 64 + l];
      acc0 = __builtin_amdgcn_mfma_f32_16x16x32_f16(
          bc_(wf), bc_(s_col[(nt0 * 9 + kt) * 64 + l]), acc0, 0, 0, 0);
      acc1 = __builtin_amdgcn_mfma_f32_16x16x32_f16(
          bc_(wf), bc_(s_col[(nt1 * 9 + kt) * 64 + l]), acc1, 0, 0, 0);
    }
    if (half == 0) __syncthreads();  // drain readers before patch rebuild
  }
  int j0 = nt0 * 16 + li, j1 = nt1 * 16 + li;
  int p0 = (y0t + (j0 >> 3)) * W + x0t + (j0 & 7);
  int p1 = (y0t + (j1 >> 3)) * W + x0t + (j1 & 7);
#pragma unroll
  for (int rg = 0; rg < 4; ++rg) {
    int och = mt * 16 + lg * 4 + rg;
    float bv = bias[och];
    x2[((size_t)(b * F + och)) * HW + p0] = fmaxf(acc0[rg] + bv, 0.f);
    x2[((size_t)(b * F + och)) * HW + p1] = fmaxf(acc1[rg] + bv, 0.f);
  }
}

// ---- om2 via MFMA -> f16 channel-last om2r[b][py][px][cdx*32+jdx] ----
__global__ __launch_bounds__(256) void dsta_om2_m(
    const float* __restrict__ x3, const uint4* __restrict__ pw2,
    const float* __restrict__ bias, _Float16* __restrict__ om2r) {
  __shared__ float s_patch[F * 100];
  __shared__ uint4 s_col[2304];
  int bid = blockIdx.x;                 // B*288
  int cs = bid & 1;
  int tile = (bid >> 1) % 144, b = bid / 288;
  int y0t = (tile / 12) * 8, x0t = (tile % 12) * 8;
  int tid = threadIdx.x;
  build_im2col<H2, W2, 256>(x3 + (size_t)b * F * HW2, y0t, x0t, s_patch,
                            (u32*)s_col, tid);
  int w = tid >> 6, l = tid & 63;
  int lg = l >> 4, li = l & 15;
#pragma unroll 1
  for (int mt = cs * 27 + w; mt < cs * 27 + 27; mt += 4) {
    uint4 wf[9];
#pragma unroll
    for (int kt = 0; kt < 9; ++kt) wf[kt] = pw2[(mt * 9 + kt) * 64 + l];
    float b4[4];
#pragma unroll
    for (int rg = 0; rg < 4; ++rg) b4[rg] = bias[mt * 16 + lg * 4 + rg];
    // channel-quad placement (uniform per 16-lane group)
    int och0 = mt * 16 + lg * 4;
    int cdx0, jdx0;
    if (och0 < 576) { cdx0 = och0 / 18; jdx0 = och0 % 18; }
    else { cdx0 = (och0 - 576) / 9; jdx0 = 18 + (och0 - 576) % 9; }
    bool contig = (och0 < 576) ? ((och0 % 18) <= 14)
                               : (((och0 - 576) % 9) <= 5);
    bool paired = contig && ((jdx0 & 1) == 0);
#pragma unroll 1
    for (int nt = 0; nt < 4; ++nt) {
      f32x4 acc = {0.f, 0.f, 0.f, 0.f};
#pragma unroll
      for (int kt = 0; kt < 9; ++kt)
        acc = __builtin_amdgcn_mfma_f32_16x16x32_f16(
            bc_(wf[kt]), bc_(s_col[(nt * 9 + kt) * 64 + l]), acc, 0, 0, 0);
      int j = nt * 16 + li;
      int gy = y0t + (j >> 3), gx = x0t + (j & 7);
      size_t pixbase = ((size_t)(b * HW2) + gy * W2 + gx) * OMP;
      if (paired) {
        u32* dst = (u32*)(om2r + pixbase + cdx0 * 32 + jdx0);
        dst[0] = pk_(acc[0] + b4[0], acc[1] + b4[1]);
        dst[1] = pk_(acc[2] + b4[2], acc[3] + b4[3]);
      } else {
#pragma unroll
        for (int rg = 0; rg < 4; ++rg) {
          int och = och0 + rg;
          int cdx, jdx;
          if (och < 576) { cdx = och / 18; jdx = och % 18; }
          else { cdx = (och - 576) / 9; jdx = 18 + (och - 576) % 9; }
          om2r[pixbase + cdx * 32 + jdx] = (_Float16)(acc[rg] + b4[rg]);
        }
      }
    }
  }
}

// ---- dcn via MFMA: 512 threads / 8 waves, 4 channels per wave ----
__global__ __launch_bounds__(512) void dsta_dcn_m(
    const float* __restrict__ x2f, const _Float16* __restrict__ om2r,
    const uint4* __restrict__ pw1, const float* __restrict__ mb,
    const float* __restrict__ dw, const float* __restrict__ db,
    float* __restrict__ dcn) {
  __shared__ uint4 s_col[2304];             // 36,864 B; aliased as s_red later
  __shared__ _Float16 s_om[8 * 27 * OMS];   // 27,648 B; first 12.8KB = patch
  // XCD-aware swizzle: 2304 = 8 XCDs * 288 contiguous tiles (one b per span)
  int bid = blockIdx.x;
  bid = (bid & 7) * 288 + (bid >> 3);
  int tile = bid % 576, b = bid / 576;
  int y0t = (tile / 24) * 8, x0t = (tile % 24) * 8;
  int tid = threadIdx.x;
  const float* xb = x2f + (size_t)b * F * HW;
  build_im2col<H, W, 512>(xb, y0t, x0t, (float*)s_om, (u32*)s_col, tid);

  int w = tid >> 6, l = tid & 63;           // w in 0..7
  int lg = l >> 4, li = l & 15;
  int hq = y0t + (l >> 3), wq = x0t + (l & 7);

  // bilinear setup (jax resize: src = dst*0.5 - 0.25, clamped taps)
  float sy = hq * 0.5f - 0.25f, sx = wq * 0.5f - 0.25f;
  float fy0 = floorf(sy), fx0 = floorf(sx);
  float gy = sy - fy0, gx = sx - fx0;
  int y0 = (int)fy0, x0 = (int)fx0;
  int y0c = min(max(y0, 0), H2 - 1), y1c = min(max(y0 + 1, 0), H2 - 1);
  int x0c = min(max(x0, 0), W2 - 1), x1c = min(max(x0 + 1, 0), W2 - 1);
  float b00 = (1.f - gy) * (1.f - gx), b01 = (1.f - gy) * gx;
  float b10 = gy * (1.f - gx), b11 = gy * gx;
  size_t p00 = ((size_t)(b * HW2) + y0c * W2 + x0c) * OMP;
  size_t p01 = ((size_t)(b * HW2) + y0c * W2 + x1c) * OMP;
  size_t p10 = ((size_t)(b * HW2) + y1c * W2 + x0c) * OMP;
  size_t p11 = ((size_t)(b * HW2) + y1c * W2 + x1c) * OMP;

  float accd[F];
#pragma unroll
  for (int o = 0; o < F; ++o) accd[o] = 0.f;
  _Float16* s_omw = s_om + w * (27 * OMS);

#pragma unroll 1
  for (int cc = 0; cc < 4; ++cc) {
    int c = w * 4 + cc;
    // (a) om1 quadrants via MFMA -> wave-private f16 LDS slab
#pragma unroll 1
    for (int mt = 0; mt < 2; ++mt) {
      uint4 wf[9];
#pragma unroll
      for (int kt = 0; kt < 9; ++kt)
        wf[kt] = pw1[(((c * 2 + mt) * 9) + kt) * 64 + l];
#pragma unroll 1
      for (int nt = 0; nt < 4; ++nt) {
        f32x4 acc = {0.f, 0.f, 0.f, 0.f};
#pragma unroll
        for (int kt = 0; kt < 9; ++kt)
          acc = __builtin_amdgcn_mfma_f32_16x16x32_f16(
              bc_(wf[kt]), bc_(s_col[(nt * 9 + kt) * 64 + l]), acc, 0, 0, 0);
        int j = nt * 16 + li;
#pragma unroll
        for (int rg = 0; rg < 4; ++rg) {
          int ch = mt * 16 + lg * 4 + rg;
          if (ch < 27) s_omw[ch * OMS + j] = (_Float16)acc[rg];
        }
      }
    }
    // (b) bilinear om2 from channel-last f16 (uint4 loads, serialized)
    const uint4* q00 = (const uint4*)(om2r + p00 + c * 32);
    const uint4* q01 = (const uint4*)(om2r + p01 + c * 32);
    const uint4* q10 = (const uint4*)(om2r + p10 + c * 32);
    const uint4* q11 = (const uint4*)(om2r + p11 + c * 32);
    float omv[27];
#pragma unroll 1
    for (int r = 0; r < 4; ++r) {
      f16x8 a0 = bc_(q00[r]), a1 = bc_(q01[r]);
      f16x8 a2 = bc_(q10[r]), a3 = bc_(q11[r]);
#pragma unroll
      for (int e = 0; e < 8; ++e) {
        int j = r * 8 + e;
        if (j < 27)
          omv[j] = b00 * (float)a0[e] + b01 * (float)a1[e] +
                   b10 * (float)a2[e] + b11 * (float)a3[e];
      }
    }
    // (c) + mask1 bias + om1 from LDS slab
#pragma unroll
    for (int j = 0; j < 27; ++j) {
      int ch = (j < 18) ? (c * 18 + j) : (576 + c * 9 + (j - 18));
      omv[j] += mb[ch] + (float)s_omw[j * OMS + l];
    }
    // (d) deformable sampling + dcn partial einsum (serialized k loop)
    const float* xc = xb + (size_t)c * HW;
#pragma unroll 1
    for (int k = 0; k < 9; ++k) {
      float m = sigmoidf_(omv[18 + k]);
      float py = (float)(hq + k / 3 - 1) + omv[2 * k];
      float px = (float)(wq + k % 3 - 1) + omv[2 * k + 1];
      float fpy = floorf(py), fpx = floorf(px);
      int yi = (int)fpy, xi = (int)fpx;
      float wy = py - fpy, wx = px - fpx;
      bool y0ok = (unsigned)yi < (unsigned)H;
      bool y1ok = (unsigned)(yi + 1) < (unsigned)H;
      bool x0ok = (unsigned)xi < (unsigned)W;
      bool x1ok = (unsigned)(xi + 1) < (unsigned)W;
      float v00 = (y0ok && x0ok) ? xc[yi * W + xi] : 0.f;
      float v01 = (y0ok && x1ok) ? xc[yi * W + xi + 1] : 0.f;
      float v10 = (y1ok && x0ok) ? xc[(yi + 1) * W + xi] : 0.f;
      float v11 = (y1ok && x1ok) ? xc[(yi + 1) * W + xi + 1] : 0.f;
      float val = (v00 * (1.f - wy) * (1.f - wx) + v01 * (1.f - wy) * wx +
                   v10 * wy * (1.f - wx) + v11 * wy * wx) * m;
#pragma unroll
      for (int o = 0; o < F; ++o)
        accd[o] = fmaf(val, dw[(o * F + c) * 9 + k], accd[o]);
    }
  }
  // two-stage cross-wave reduction (stride 33 -> conflict-free)
  __syncthreads();
  float* s_red = (float*)s_col;             // 8448 floats needed <= 9216 cap
  if (w >= 4) {
#pragma unroll
    for (int o = 0; o < F; ++o) s_red[((w - 4) * 64 + l) * 33 + o] = accd[o];
  }
  __syncthreads();
  if (w < 4) {
#pragma unroll
    for (int o = 0; o < F; ++o) accd[o] += s_red[(w * 64 + l) * 33 + o];
  }
  __syncthreads();
  if (w < 4) {
#pragma unroll
    for (int o = 0; o < F; ++o) s_red[(w * 64 + l) * 33 + o] = accd[o];
  }
  __syncthreads();
  int px_ = tid & 63, og = tid >> 6;        // og 0..7, 4 outputs each
  int hp = y0t + (px_ >> 3), wp = x0t + (px_ & 7);
#pragma unroll
  for (int oo = 0; oo < 4; ++oo) {
    int o = og * 4 + oo;
    float s = db[o];
#pragma unroll
    for (int w2 = 0; w2 < 4; ++w2) s += s_red[(w2 * 64 + px_) * 33 + o];
    dcn[((size_t)(b * F + o)) * HW + hp * W + wp] = fmaxf(s, 0.f);
  }
}

// ---- out via MFMA: 3x3 p1 conv 32->64 + bias + relu, FP32 output ----
__global__ __launch_bounds__(256) void dsta_out_m(
    const float* __restrict__ dcn, const uint4* __restrict__ pco,
    const float* __restrict__ bias, float* __restrict__ out) {
  __shared__ float s_patch[F * 100];
  __shared__ uint4 s_col[2304];
  int bid = blockIdx.x;                 // B*576
  int tile = bid % 576, b = bid / 576;
  int y0t = (tile / 24) * 8, x0t = (tile % 24) * 8;
  int tid = threadIdx.x;
  build_im2col<H, W, 256>(dcn + (size_t)b * F * HW, y0t, x0t, s_patch,
                          (u32*)s_col, tid);
  int w = tid >> 6, l = tid & 63;
  int lg = l >> 4, li = l & 15;
  int mt = w;
  f32x4 acc[4];
#pragma unroll
  for (int nt = 0; nt < 4; ++nt) acc[nt] = {0.f, 0.f, 0.f, 0.f};
#pragma unroll 1
  for (int kt = 0; kt < 9; ++kt) {
    uint4 wf = pco[(mt * 9 + kt) * 64 + l];
#pragma unroll
    for (int nt = 0; nt < 4; ++nt)
      acc[nt] = __builtin_amdgcn_mfma_f32_16x16x32_f16(
          bc_(wf), bc_(s_col[(nt * 9 + kt) * 64 + l]), acc[nt], 0, 0, 0);
  }
#pragma unroll
  for (int nt = 0; nt < 4; ++nt) {
    int j = nt * 16 + li;
    int p = (y0t + (j >> 3)) * W + x0t + (j & 7);
#pragma unroll
    for (int rg = 0; rg < 4; ++rg) {
      int och = mt * 16 + lg * 4 + rg;  // 0..63
      out[((size_t)(b * N + och)) * HW + p] = fmaxf(acc[nt][rg] + bias[och], 0.f);
    }
  }
}

extern "C" void kernel_launch(void* const* d_in, const int* in_sizes, int n_in,
                              void* d_out, int out_size, void* d_ws, size_t ws_size,
                              hipStream_t stream) {
  float* out = (float*)d_out;
  const int fill_grid = (out_size + 255) / 256;

  static const int idmap[18]  = {0,1,2,3,4,5,6,7,8,9,10,11,12,13,14,15,16,17};
  static const int alphamap[18] = {17,3,2,16,0,1,9,8,11,10,7,6,13,12,5,4,15,14};
  const int* map = nullptr;
  if (n_in == 18 && in_sizes[0] == 9437184) map = idmap;
  else if (n_in == 18 && in_sizes[17] == 9437184) map = alphamap;
  if (!map) {
    dsta_fill<<<fill_grid, 256, 0, stream>>>(out, out_size, 2.0e6f);
    return;
  }
  if (in_sizes[map[8]] != 248832 || in_sizes[map[16]] != 18432) {
    dsta_fill<<<fill_grid, 256, 0, stream>>>(out, out_size, 3.0e6f);
    return;
  }

  const float* x       = (const float*)d_in[map[0]];
  const float* conv1_w = (const float*)d_in[map[1]];
  const float* conv1_b = (const float*)d_in[map[2]];
  const float* sa_w    = (const float*)d_in[map[3]];
  const float* ca_w1   = (const float*)d_in[map[4]];
  const float* ca_w2   = (const float*)d_in[map[5]];
  const float* fuse_w  = (const float*)d_in[map[6]];
  const float* fuse_b  = (const float*)d_in[map[7]];
  const float* mask1_w = (const float*)d_in[map[8]];
  const float* mask1_b = (const float*)d_in[map[9]];
  const float* down_w  = (const float*)d_in[map[10]];
  const float* down_b  = (const float*)d_in[map[11]];
  const float* mask2_w = (const float*)d_in[map[12]];
  const float* mask2_b = (const float*)d_in[map[13]];
  const float* dcn_w   = (const float*)d_in[map[14]];
  const float* dcn_b   = (const float*)d_in[map[15]];
  const float* out_w   = (const float*)d_in[map[16]];
  const float* out_b   = (const float*)d_in[map[17]];

  float* ws = (float*)d_ws;
  float* x2    = ws;                                 // 4,718,592 f32
  float* x2f   = x2  + (size_t)B * F * HW;           // 4,718,592 f32
  float* x3    = x2f + (size_t)B * F * HW;           // 1,179,648 f32
  float* stats = x3  + (size_t)B * F * HW2;          //   294,912 f32
  float* ap    = stats + (size_t)B * 2 * HW;
  float* mp    = ap + B * F;
  float* sig   = mp + B * F;
  _Float16* om2r = (_Float16*)(sig + B * F);         // B*HW2*OMP f16 = 75.5 MB
  u32* pc1 = (u32*)(om2r + (size_t)B * HW2 * OMP);   // 9,216 u32
  u32* pco = pc1 + 9216;                             // 9,216 u32
  float* dcn   = x2;  // alias: x2 dead after dsta_safuse

  // pw1/pw2 in d_out scratch (consumed before dsta_out_m writes d_out).
  u32* pw1 = (u32*)d_out;              // 147,456 u32
  u32* pw2 = pw1 + 147456;             // 124,416 u32

  const size_t base_f32 = 10912128;
  const size_t need = base_f32 * 4ull + (size_t)B * HW2 * OMP * 2ull +
                      2ull * 9216 * 4ull;            // ~119.2 MB
  if (ws_size < need) {
    dsta_fill<<<fill_grid, 256, 0, stream>>>(
        out, out_size, 1.0e6f + (float)(ws_size >> 20));
    return;
  }

  dsta_pack<<<1134, 256, 0, stream>>>(mask1_w, mask2_w, conv1_w, out_w,
                                      pw1, pw2, pc1, pco);
  dsta_conv1_m<<<2304, 256, 0, stream>>>(x, (const uint4*)pc1, conv1_b, x2);
  dsta_stats<<<576, 256, 0, stream>>>(x2, stats);
  dsta_ca_red<<<128, 256, 0, stream>>>(x2, ap, mp);
  dsta_ca_mlp<<<1, 128, 0, stream>>>(ap, mp, ca_w1, ca_w2, sig);
  dsta_safuse<<<576, 256, 0, stream>>>(stats, x2, sig, sa_w, fuse_w, fuse_b,
                                       x2f);
  dsta_down<<<576, 256, 0, stream>>>(x2f, down_w, down_b, x3);
  dsta_om2_m<<<1152, 256, 0, stream>>>(x3, (const uint4*)pw2, mask2_b, om2r);
  dsta_dcn_m<<<2304, 512, 0, stream>>>(x2f, om2r, (const uint4*)pw1,
                                       mask1_b, dcn_w, dcn_b, dcn);
  dsta_out_m<<<2304, 256, 0, stream>>>(dcn, (const uint4*)pco, out_b, out);
}

// Round 16
// 849.681 us; speedup vs baseline: 1.1072x; 1.1072x over previous
//
#include <hip/hip_runtime.h>
#include <hip/hip_bf16.h>
#include <math.h>

// Fused CBAM + deformable-conv pipeline. R16 = R14 (best: 853.6us; dcn 490us
// @ VGPR 76 / 34% occ) + fast-path __expf sigmoid. R15's 512-thread dcn
// regressed (64.5KB LDS -> 1 block/CU); reverted.

constexpr int B = 4, N = 64, F = 32;
constexpr int H = 192, W = 192, HW = H * W;
constexpr int H2 = 96, W2 = 96, HW2 = H2 * W2;
constexpr int OMP = 1024;  // padded per-pixel channel stride for om2r
constexpr int OMS = 64;    // s_omw per-channel stride

using u32 = unsigned int;
using f16x8 = __attribute__((ext_vector_type(8))) _Float16;
using f32x4 = __attribute__((ext_vector_type(4))) float;

__device__ __forceinline__ float sigmoidf_(float v) {
  return 1.f / (1.f + __expf(-v));
}
__device__ __forceinline__ f16x8 bc_(uint4 u) {
  union { uint4 u; f16x8 h; } x; x.u = u; return x.h;
}
__device__ __forceinline__ u32 pk_(float a, float b) {
  union { u32 u; _Float16 h[2]; } x; x.h[0] = (_Float16)a; x.h[1] = (_Float16)b;
  return x.u;
}

// ---- diagnostic fill ----
__global__ __launch_bounds__(256) void dsta_fill(float* __restrict__ out,
                                                 int n, float v) {
  int i = blockIdx.x * 256 + threadIdx.x;
  if (i < n) out[i] = v;
}

// ---- channel mean & max maps -> stats(B,2,H,W) ----
__global__ __launch_bounds__(256) void dsta_stats(
    const float* __restrict__ x2, float* __restrict__ stats) {
  int idx = blockIdx.x * 256 + threadIdx.x;
  int p = idx % HW, b = idx / HW;
  float s = 0.f, m = -3.4e38f;
  for (int c = 0; c < F; ++c) {
    float v = x2[((size_t)(b * F + c)) * HW + p];
    s += v; m = fmaxf(m, v);
  }
  stats[((size_t)(b * 2 + 0)) * HW + p] = s * (1.f / F);
  stats[((size_t)(b * 2 + 1)) * HW + p] = m;
}

// ---- per-(b,c) spatial mean & max ----
__global__ __launch_bounds__(256) void dsta_ca_red(
    const float* __restrict__ x2, float* __restrict__ ap, float* __restrict__ mp) {
  __shared__ float ss[256], sm[256];
  int bc = blockIdx.x;
  const float* src = x2 + (size_t)bc * HW;
  float s = 0.f, m = -3.4e38f;
  for (int i = threadIdx.x; i < HW; i += 256) {
    float v = src[i]; s += v; m = fmaxf(m, v);
  }
  ss[threadIdx.x] = s; sm[threadIdx.x] = m;
  __syncthreads();
  for (int o = 128; o > 0; o >>= 1) {
    if (threadIdx.x < o) {
      ss[threadIdx.x] += ss[threadIdx.x + o];
      sm[threadIdx.x] = fmaxf(sm[threadIdx.x], sm[threadIdx.x + o]);
    }
    __syncthreads();
  }
  if (threadIdx.x == 0) { ap[bc] = ss[0] * (1.f / HW); mp[bc] = sm[0]; }
}

// ---- channel-attention MLP ----
__global__ __launch_bounds__(128) void dsta_ca_mlp(
    const float* __restrict__ ap, const float* __restrict__ mp,
    const float* __restrict__ w1, const float* __restrict__ w2,
    float* __restrict__ sig) {
  int t = threadIdx.x;
  if (t >= B * F) return;
  int b = t / F, co = t % F;
  float accA = 0.f, accB = 0.f;
  for (int j = 0; j < F / 2; ++j) {
    float hA = 0.f, hB = 0.f;
    for (int c = 0; c < F; ++c) {
      float wv = w1[j * F + c];
      hA = fmaf(wv, ap[b * F + c], hA);
      hB = fmaf(wv, mp[b * F + c], hB);
    }
    hA = fmaxf(hA, 0.f); hB = fmaxf(hB, 0.f);
    float wv2 = w2[co * (F / 2) + j];
    accA = fmaf(wv2, hA, accA);
    accB = fmaf(wv2, hB, accB);
  }
  sig[t] = sigmoidf_(accA + accB);
}

// ---- fused spatial-attention (7x7 conv + silu) + channel-att + 1x1 fuse ----
__global__ __launch_bounds__(256) void dsta_safuse(
    const float* __restrict__ stats, const float* __restrict__ x2,
    const float* __restrict__ sig, const float* __restrict__ sa_w,
    const float* __restrict__ fw, const float* __restrict__ fb,
    float* __restrict__ x2f) {
  int idx = blockIdx.x * 256 + threadIdx.x;   // B*HW
  int p = idx % HW, b = idx / HW;
  int h = p / W, w = p % W;
  float acc[F];
#pragma unroll
  for (int j = 0; j < F; ++j) acc[j] = 0.f;   // sa has no bias
#pragma unroll 1
  for (int ci = 0; ci < 2; ++ci) {
    const float* sp = stats + ((size_t)(b * 2 + ci)) * HW;
#pragma unroll 1
    for (int ky = 0; ky < 7; ++ky) {
      int yy = h + ky - 3;
      float tap[7];
#pragma unroll
      for (int kx = 0; kx < 7; ++kx) {
        int xx = w + kx - 3;
        tap[kx] = (yy >= 0 && yy < H && xx >= 0 && xx < W) ? sp[yy * W + xx] : 0.f;
      }
#pragma unroll
      for (int j = 0; j < F; ++j) {
        const float* wp = sa_w + ((size_t)(j * 2 + ci) * 49) + ky * 7;
#pragma unroll
        for (int kx = 0; kx < 7; ++kx) acc[j] = fmaf(wp[kx], tap[kx], acc[j]);
      }
    }
  }
  float accf[F];
#pragma unroll
  for (int o = 0; o < F; ++o) accf[o] = fb[o];
#pragma unroll 1
  for (int j = 0; j < F; ++j) {
    float v = acc[j];
    float asv = sigmoidf_(v) * v;
#pragma unroll
    for (int o = 0; o < F; ++o) accf[o] = fmaf(fw[o * 2 * F + j], asv, accf[o]);
  }
#pragma unroll 1
  for (int c = 0; c < F; ++c) {
    float xc = sig[b * F + c] * x2[((size_t)(b * F + c)) * HW + p];
#pragma unroll
    for (int o = 0; o < F; ++o)
      accf[o] = fmaf(fw[o * 2 * F + F + c], xc, accf[o]);
  }
#pragma unroll
  for (int o = 0; o < F; ++o)
    x2f[((size_t)(b * F + o)) * HW + p] = fmaxf(accf[o], 0.f);
}

// ---- down: 3x3 s2 p1 conv 32->32 + relu ----
__global__ __launch_bounds__(256) void dsta_down(
    const float* __restrict__ x2f, const float* __restrict__ wgt,
    const float* __restrict__ bias, float* __restrict__ x3) {
  int idx = blockIdx.x * 256 + threadIdx.x;
  int p = idx % HW2; int r = idx / HW2;
  int g = r % 4, b = r / 4;
  int h2 = p / W2, w2 = p % W2;
  float acc[8];
#pragma unroll
  for (int j = 0; j < 8; ++j) acc[j] = bias[g * 8 + j];
  for (int ci = 0; ci < F; ++ci) {
    const float* xp = x2f + ((size_t)(b * F + ci)) * HW;
    float tap[9];
#pragma unroll
    for (int t = 0; t < 9; ++t) {
      int yy = 2 * h2 + t / 3 - 1, xx = 2 * w2 + t % 3 - 1;
      tap[t] = (yy >= 0 && yy < H && xx >= 0 && xx < W) ? xp[yy * W + xx] : 0.f;
    }
#pragma unroll
    for (int j = 0; j < 8; ++j) {
      const float* wp = wgt + ((size_t)(g * 8 + j) * F + ci) * 9;
#pragma unroll
      for (int t = 0; t < 9; ++t) acc[j] = fmaf(wp[t], tap[t], acc[j]);
    }
  }
#pragma unroll
  for (int j = 0; j < 8; ++j)
    x3[((size_t)(b * F + g * 8 + j)) * HW2 + p] = fmaxf(acc[j], 0.f);
}

// ---- weight frag-pack (fp16 pairs), same k-map as im2col builder ----
__global__ __launch_bounds__(256) void dsta_pack(
    const float* __restrict__ mw, const float* __restrict__ m2w,
    const float* __restrict__ c1w, const float* __restrict__ ow,
    u32* __restrict__ pw1, u32* __restrict__ pw2,
    u32* __restrict__ pc1, u32* __restrict__ pco) {
  int i = blockIdx.x * 256 + threadIdx.x;   // 290,304 total
  int r = i & 3, l = (i >> 2) & 63;
  int k0 = 8 * (l >> 4) + 2 * r;            // base within kt tile
  if (i < 147456) {
    int kt = (i >> 8) % 9, q = (i >> 8) / 9;
    int mt = q & 1, c = q >> 1;
    int ochl = mt * 16 + (l & 15);
    int kk = kt * 32 + k0;
    float v0 = 0.f, v1 = 0.f;
    if (ochl < 27) {
      int ochg = ochl < 18 ? c * 18 + ochl : 576 + c * 9 + (ochl - 18);
      v0 = mw[(size_t)ochg * 288 + kk];
      v1 = mw[(size_t)ochg * 288 + kk + 1];
    }
    pw1[i] = pk_(v0, v1);
  } else if (i < 271872) {
    int i2 = i - 147456;
    int kt = (i2 >> 8) % 9, mt = (i2 >> 8) / 9;
    int och = mt * 16 + (l & 15);
    int kk = kt * 32 + k0;
    pw2[i2] = pk_(m2w[(size_t)och * 288 + kk], m2w[(size_t)och * 288 + kk + 1]);
  } else if (i < 281088) {
    int i3 = i - 271872;
    int kt = (i3 >> 8) % 9, q = (i3 >> 8) / 9;
    int mt = q & 1, half = q >> 1;
    int och = mt * 16 + (l & 15);             // < 32
    int kk = half * 288 + kt * 32 + k0;       // global k into 576
    pc1[i3] = pk_(c1w[(size_t)och * 576 + kk], c1w[(size_t)och * 576 + kk + 1]);
  } else {
    int i4 = i - 281088;
    int kt = (i4 >> 8) % 9, mt = (i4 >> 8) / 9;  // mt 0..3
    int och = mt * 16 + (l & 15);             // < 64
    int kk = kt * 32 + k0;
    pco[i4] = pk_(ow[(size_t)och * 288 + kk], ow[(size_t)och * 288 + kk + 1]);
  }
}

// ---- cooperative im2col builder: 8x8 px tile, 32 ci -> fp16 frags in LDS ----
template <int SH, int SW>
__device__ __forceinline__ void build_im2col(
    const float* __restrict__ src, int y0t, int x0t,
    float* __restrict__ patch, u32* __restrict__ im2, int tid) {
  for (int i = tid; i < F * 100; i += 256) {
    int ci = i / 100, rr = i % 100;
    int yy = y0t + rr / 10 - 1, xx = x0t + rr % 10 - 1;
    patch[i] = (yy >= 0 && yy < SH && xx >= 0 && xx < SW)
                   ? src[(size_t)ci * (SH * SW) + yy * SW + xx] : 0.f;
  }
  __syncthreads();
  for (int i = tid; i < 9216; i += 256) {
    int r = i & 3, l = (i >> 2) & 63;
    int kt = (i >> 8) % 9, nt = (i >> 8) / 9;
    int j = nt * 16 + (l & 15);
    int ly = j >> 3, lx = j & 7;
    int k0 = kt * 32 + 8 * (l >> 4) + 2 * r;
    int ci0 = k0 / 9, t0 = k0 - 9 * ci0;
    int k1 = k0 + 1;
    int ci1 = k1 / 9, t1 = k1 - 9 * ci1;
    float v0 = patch[ci0 * 100 + (ly + t0 / 3) * 10 + (lx + t0 % 3)];
    float v1 = patch[ci1 * 100 + (ly + t1 / 3) * 10 + (lx + t1 % 3)];
    im2[i] = pk_(v0, v1);
  }
  __syncthreads();
}

// ---- conv1 via MFMA: 3x3 p1 conv 64->32 + bias + relu (two K-halves) ----
__global__ __launch_bounds__(256) void dsta_conv1_m(
    const float* __restrict__ x, const uint4* __restrict__ pc1,
    const float* __restrict__ bias, float* __restrict__ x2) {
  __shared__ float s_patch[F * 100];
  __shared__ uint4 s_col[2304];
  int bid = blockIdx.x;                 // B*576
  int tile = bid % 576, b = bid / 576;
  int y0t = (tile / 24) * 8, x0t = (tile % 24) * 8;
  int tid = threadIdx.x;
  int w = tid >> 6, l = tid & 63;
  int lg = l >> 4, li = l & 15;
  int mt = w & 1;
  int nt0 = w >> 1, nt1 = 2 + (w >> 1);
  f32x4 acc0 = {0.f, 0.f, 0.f, 0.f}, acc1 = {0.f, 0.f, 0.f, 0.f};
#pragma unroll 1
  for (int half = 0; half < 2; ++half) {
    build_im2col<H, W>(x + ((size_t)(b * N + half * F)) * HW, y0t, x0t,
                       s_patch, (u32*)s_col, tid);
#pragma unroll 1
    for (int kt = 0; kt < 9; ++kt) {
      uint4 wf = pc1[(((half * 2 + mt) * 9) + kt) * 64 + l];
      acc0 = __builtin_amdgcn_mfma_f32_16x16x32_f16(
          bc_(wf), bc_(s_col[(nt0 * 9 + kt) * 64 + l]), acc0, 0, 0, 0);
      acc1 = __builtin_amdgcn_mfma_f32_16x16x32_f16(
          bc_(wf), bc_(s_col[(nt1 * 9 + kt) * 64 + l]), acc1, 0, 0, 0);
    }
    if (half == 0) __syncthreads();  // drain readers before patch rebuild
  }
  int j0 = nt0 * 16 + li, j1 = nt1 * 16 + li;
  int p0 = (y0t + (j0 >> 3)) * W + x0t + (j0 & 7);
  int p1 = (y0t + (j1 >> 3)) * W + x0t + (j1 & 7);
#pragma unroll
  for (int rg = 0; rg < 4; ++rg) {
    int och = mt * 16 + lg * 4 + rg;
    float bv = bias[och];
    x2[((size_t)(b * F + och)) * HW + p0] = fmaxf(acc0[rg] + bv, 0.f);
    x2[((size_t)(b * F + och)) * HW + p1] = fmaxf(acc1[rg] + bv, 0.f);
  }
}

// ---- om2 via MFMA -> f16 channel-last om2r[b][py][px][cdx*32+jdx] ----
__global__ __launch_bounds__(256) void dsta_om2_m(
    const float* __restrict__ x3, const uint4* __restrict__ pw2,
    const float* __restrict__ bias, _Float16* __restrict__ om2r) {
  __shared__ float s_patch[F * 100];
  __shared__ uint4 s_col[2304];
  int bid = blockIdx.x;                 // B*288
  int cs = bid & 1;
  int tile = (bid >> 1) % 144, b = bid / 288;
  int y0t = (tile / 12) * 8, x0t = (tile % 12) * 8;
  int tid = threadIdx.x;
  build_im2col<H2, W2>(x3 + (size_t)b * F * HW2, y0t, x0t, s_patch,
                       (u32*)s_col, tid);
  int w = tid >> 6, l = tid & 63;
  int lg = l >> 4, li = l & 15;
#pragma unroll 1
  for (int mt = cs * 27 + w; mt < cs * 27 + 27; mt += 4) {
    uint4 wf[9];
#pragma unroll
    for (int kt = 0; kt < 9; ++kt) wf[kt] = pw2[(mt * 9 + kt) * 64 + l];
    float b4[4];
#pragma unroll
    for (int rg = 0; rg < 4; ++rg) b4[rg] = bias[mt * 16 + lg * 4 + rg];
    // channel-quad placement (uniform per 16-lane group)
    int och0 = mt * 16 + lg * 4;
    int cdx0, jdx0;
    if (och0 < 576) { cdx0 = och0 / 18; jdx0 = och0 % 18; }
    else { cdx0 = (och0 - 576) / 9; jdx0 = 18 + (och0 - 576) % 9; }
    bool contig = (och0 < 576) ? ((och0 % 18) <= 14)
                               : (((och0 - 576) % 9) <= 5);
    bool paired = contig && ((jdx0 & 1) == 0);
#pragma unroll 1
    for (int nt = 0; nt < 4; ++nt) {
      f32x4 acc = {0.f, 0.f, 0.f, 0.f};
#pragma unroll
      for (int kt = 0; kt < 9; ++kt)
        acc = __builtin_amdgcn_mfma_f32_16x16x32_f16(
            bc_(wf[kt]), bc_(s_col[(nt * 9 + kt) * 64 + l]), acc, 0, 0, 0);
      int j = nt * 16 + li;
      int gy = y0t + (j >> 3), gx = x0t + (j & 7);
      size_t pixbase = ((size_t)(b * HW2) + gy * W2 + gx) * OMP;
      if (paired) {
        u32* dst = (u32*)(om2r + pixbase + cdx0 * 32 + jdx0);
        dst[0] = pk_(acc[0] + b4[0], acc[1] + b4[1]);
        dst[1] = pk_(acc[2] + b4[2], acc[3] + b4[3]);
      } else {
#pragma unroll
        for (int rg = 0; rg < 4; ++rg) {
          int och = och0 + rg;
          int cdx, jdx;
          if (och < 576) { cdx = och / 18; jdx = och % 18; }
          else { cdx = (och - 576) / 9; jdx = 18 + (och - 576) % 9; }
          om2r[pixbase + cdx * 32 + jdx] = (_Float16)(acc[rg] + b4[rg]);
        }
      }
    }
  }
}

// ---- dcn via MFMA: per-tile om1 GEMM + bilinear om2r + DCNv2 sampling ----
// R14-lean body (best measured): direct uint4 gathers, serialized loops.
__global__ __launch_bounds__(256) void dsta_dcn_m(
    const float* __restrict__ x2f, const _Float16* __restrict__ om2r,
    const uint4* __restrict__ pw1, const float* __restrict__ mb,
    const float* __restrict__ dw, const float* __restrict__ db,
    float* __restrict__ dcn) {
  __shared__ uint4 s_col[2304];             // 36,864 B; aliased as s_red later
  __shared__ _Float16 s_om[4 * 27 * OMS];   // 13,824 B; first 12.8KB = patch
  // XCD-aware swizzle: 2304 = 8 XCDs * 288 contiguous tiles (one b per span)
  int bid = blockIdx.x;
  bid = (bid & 7) * 288 + (bid >> 3);
  int tile = bid % 576, b = bid / 576;
  int y0t = (tile / 24) * 8, x0t = (tile % 24) * 8;
  int tid = threadIdx.x;
  const float* xb = x2f + (size_t)b * F * HW;
  build_im2col<H, W>(xb, y0t, x0t, (float*)s_om, (u32*)s_col, tid);

  int w = tid >> 6, l = tid & 63;
  int lg = l >> 4, li = l & 15;
  int hq = y0t + (l >> 3), wq = x0t + (l & 7);

  // bilinear setup (jax resize: src = dst*0.5 - 0.25, clamped taps)
  float sy = hq * 0.5f - 0.25f, sx = wq * 0.5f - 0.25f;
  float fy0 = floorf(sy), fx0 = floorf(sx);
  float gy = sy - fy0, gx = sx - fx0;
  int y0 = (int)fy0, x0 = (int)fx0;
  int y0c = min(max(y0, 0), H2 - 1), y1c = min(max(y0 + 1, 0), H2 - 1);
  int x0c = min(max(x0, 0), W2 - 1), x1c = min(max(x0 + 1, 0), W2 - 1);
  float b00 = (1.f - gy) * (1.f - gx), b01 = (1.f - gy) * gx;
  float b10 = gy * (1.f - gx), b11 = gy * gx;
  size_t p00 = ((size_t)(b * HW2) + y0c * W2 + x0c) * OMP;
  size_t p01 = ((size_t)(b * HW2) + y0c * W2 + x1c) * OMP;
  size_t p10 = ((size_t)(b * HW2) + y1c * W2 + x0c) * OMP;
  size_t p11 = ((size_t)(b * HW2) + y1c * W2 + x1c) * OMP;

  float accd[F];
#pragma unroll
  for (int o = 0; o < F; ++o) accd[o] = 0.f;
  _Float16* s_omw = s_om + w * (27 * OMS);

#pragma unroll 1
  for (int cc = 0; cc < 8; ++cc) {
    int c = w * 8 + cc;
    // (a) om1 quadrants via MFMA -> wave-private f16 LDS slab
#pragma unroll 1
    for (int mt = 0; mt < 2; ++mt) {
      uint4 wf[9];
#pragma unroll
      for (int kt = 0; kt < 9; ++kt)
        wf[kt] = pw1[(((c * 2 + mt) * 9) + kt) * 64 + l];
#pragma unroll 1
      for (int nt = 0; nt < 4; ++nt) {
        f32x4 acc = {0.f, 0.f, 0.f, 0.f};
#pragma unroll
        for (int kt = 0; kt < 9; ++kt)
          acc = __builtin_amdgcn_mfma_f32_16x16x32_f16(
              bc_(wf[kt]), bc_(s_col[(nt * 9 + kt) * 64 + l]), acc, 0, 0, 0);
        int j = nt * 16 + li;
#pragma unroll
        for (int rg = 0; rg < 4; ++rg) {
          int ch = mt * 16 + lg * 4 + rg;
          if (ch < 27) s_omw[ch * OMS + j] = (_Float16)acc[rg];
        }
      }
    }
    // (b) bilinear om2 from channel-last f16 (uint4 loads, serialized)
    const uint4* q00 = (const uint4*)(om2r + p00 + c * 32);
    const uint4* q01 = (const uint4*)(om2r + p01 + c * 32);
    const uint4* q10 = (const uint4*)(om2r + p10 + c * 32);
    const uint4* q11 = (const uint4*)(om2r + p11 + c * 32);
    float omv[27];
#pragma unroll 1
    for (int r = 0; r < 4; ++r) {
      f16x8 a0 = bc_(q00[r]), a1 = bc_(q01[r]);
      f16x8 a2 = bc_(q10[r]), a3 = bc_(q11[r]);
#pragma unroll
      for (int e = 0; e < 8; ++e) {
        int j = r * 8 + e;
        if (j < 27)
          omv[j] = b00 * (float)a0[e] + b01 * (float)a1[e] +
                   b10 * (float)a2[e] + b11 * (float)a3[e];
      }
    }
    // (c) + mask1 bias + om1 from LDS slab
#pragma unroll
    for (int j = 0; j < 27; ++j) {
      int ch = (j < 18) ? (c * 18 + j) : (576 + c * 9 + (j - 18));
      omv[j] += mb[ch] + (float)s_omw[j * OMS + l];
    }
    // (d) deformable sampling + dcn partial einsum (serialized k loop)
    const float* xc = xb + (size_t)c * HW;
#pragma unroll 1
    for (int k = 0; k < 9; ++k) {
      float m = sigmoidf_(omv[18 + k]);
      float py = (float)(hq + k / 3 - 1) + omv[2 * k];
      float px = (float)(wq + k % 3 - 1) + omv[2 * k + 1];
      float fpy = floorf(py), fpx = floorf(px);
      int yi = (int)fpy, xi = (int)fpx;
      float wy = py - fpy, wx = px - fpx;
      bool y0ok = (unsigned)yi < (unsigned)H;
      bool y1ok = (unsigned)(yi + 1) < (unsigned)H;
      bool x0ok = (unsigned)xi < (unsigned)W;
      bool x1ok = (unsigned)(xi + 1) < (unsigned)W;
      float v00 = (y0ok && x0ok) ? xc[yi * W + xi] : 0.f;
      float v01 = (y0ok && x1ok) ? xc[yi * W + xi + 1] : 0.f;
      float v10 = (y1ok && x0ok) ? xc[(yi + 1) * W + xi] : 0.f;
      float v11 = (y1ok && x1ok) ? xc[(yi + 1) * W + xi + 1] : 0.f;
      float val = (v00 * (1.f - wy) * (1.f - wx) + v01 * (1.f - wy) * wx +
                   v10 * wy * (1.f - wx) + v11 * wy * wx) * m;
#pragma unroll
      for (int o = 0; o < F; ++o)
        accd[o] = fmaf(val, dw[(o * F + c) * 9 + k], accd[o]);
    }
  }
  // cross-wave reduction (stride 33 -> conflict-free)
  __syncthreads();
  float* s_red = (float*)s_col;
#pragma unroll
  for (int o = 0; o < F; ++o) s_red[(w * 64 + l) * 33 + o] = accd[o];
  __syncthreads();
  int px_ = tid & 63, og = tid >> 6;
  int hp = y0t + (px_ >> 3), wp = x0t + (px_ & 7);
#pragma unroll
  for (int oo = 0; oo < 8; ++oo) {
    int o = og * 8 + oo;
    float s = db[o];
#pragma unroll
    for (int w2 = 0; w2 < 4; ++w2) s += s_red[(w2 * 64 + px_) * 33 + o];
    dcn[((size_t)(b * F + o)) * HW + hp * W + wp] = fmaxf(s, 0.f);
  }
}

// ---- out via MFMA: 3x3 p1 conv 32->64 + bias + relu, FP32 output ----
__global__ __launch_bounds__(256) void dsta_out_m(
    const float* __restrict__ dcn, const uint4* __restrict__ pco,
    const float* __restrict__ bias, float* __restrict__ out) {
  __shared__ float s_patch[F * 100];
  __shared__ uint4 s_col[2304];
  int bid = blockIdx.x;                 // B*576
  int tile = bid % 576, b = bid / 576;
  int y0t = (tile / 24) * 8, x0t = (tile % 24) * 8;
  int tid = threadIdx.x;
  build_im2col<H, W>(dcn + (size_t)b * F * HW, y0t, x0t, s_patch,
                     (u32*)s_col, tid);
  int w = tid >> 6, l = tid & 63;
  int lg = l >> 4, li = l & 15;
  int mt = w;
  f32x4 acc[4];
#pragma unroll
  for (int nt = 0; nt < 4; ++nt) acc[nt] = {0.f, 0.f, 0.f, 0.f};
#pragma unroll 1
  for (int kt = 0; kt < 9; ++kt) {
    uint4 wf = pco[(mt * 9 + kt) * 64 + l];
#pragma unroll
    for (int nt = 0; nt < 4; ++nt)
      acc[nt] = __builtin_amdgcn_mfma_f32_16x16x32_f16(
          bc_(wf), bc_(s_col[(nt * 9 + kt) * 64 + l]), acc[nt], 0, 0, 0);
  }
#pragma unroll
  for (int nt = 0; nt < 4; ++nt) {
    int j = nt * 16 + li;
    int p = (y0t + (j >> 3)) * W + x0t + (j & 7);
#pragma unroll
    for (int rg = 0; rg < 4; ++rg) {
      int och = mt * 16 + lg * 4 + rg;  // 0..63
      out[((size_t)(b * N + och)) * HW + p] = fmaxf(acc[nt][rg] + bias[och], 0.f);
    }
  }
}

extern "C" void kernel_launch(void* const* d_in, const int* in_sizes, int n_in,
                              void* d_out, int out_size, void* d_ws, size_t ws_size,
                              hipStream_t stream) {
  float* out = (float*)d_out;
  const int fill_grid = (out_size + 255) / 256;

  static const int idmap[18]  = {0,1,2,3,4,5,6,7,8,9,10,11,12,13,14,15,16,17};
  static const int alphamap[18] = {17,3,2,16,0,1,9,8,11,10,7,6,13,12,5,4,15,14};
  const int* map = nullptr;
  if (n_in == 18 && in_sizes[0] == 9437184) map = idmap;
  else if (n_in == 18 && in_sizes[17] == 9437184) map = alphamap;
  if (!map) {
    dsta_fill<<<fill_grid, 256, 0, stream>>>(out, out_size, 2.0e6f);
    return;
  }
  if (in_sizes[map[8]] != 248832 || in_sizes[map[16]] != 18432) {
    dsta_fill<<<fill_grid, 256, 0, stream>>>(out, out_size, 3.0e6f);
    return;
  }

  const float* x       = (const float*)d_in[map[0]];
  const float* conv1_w = (const float*)d_in[map[1]];
  const float* conv1_b = (const float*)d_in[map[2]];
  const float* sa_w    = (const float*)d_in[map[3]];
  const float* ca_w1   = (const float*)d_in[map[4]];
  const float* ca_w2   = (const float*)d_in[map[5]];
  const float* fuse_w  = (const float*)d_in[map[6]];
  const float* fuse_b  = (const float*)d_in[map[7]];
  const float* mask1_w = (const float*)d_in[map[8]];
  const float* mask1_b = (const float*)d_in[map[9]];
  const float* down_w  = (const float*)d_in[map[10]];
  const float* down_b  = (const float*)d_in[map[11]];
  const float* mask2_w = (const float*)d_in[map[12]];
  const float* mask2_b = (const float*)d_in[map[13]];
  const float* dcn_w   = (const float*)d_in[map[14]];
  const float* dcn_b   = (const float*)d_in[map[15]];
  const float* out_w   = (const float*)d_in[map[16]];
  const float* out_b   = (const float*)d_in[map[17]];

  float* ws = (float*)d_ws;
  float* x2    = ws;                                 // 4,718,592 f32
  float* x2f   = x2  + (size_t)B * F * HW;           // 4,718,592 f32
  float* x3    = x2f + (size_t)B * F * HW;           // 1,179,648 f32
  float* stats = x3  + (size_t)B * F * HW2;          //   294,912 f32
  float* ap    = stats + (size_t)B * 2 * HW;
  float* mp    = ap + B * F;
  float* sig   = mp + B * F;
  _Float16* om2r = (_Float16*)(sig + B * F);         // B*HW2*OMP f16 = 75.5 MB
  u32* pc1 = (u32*)(om2r + (size_t)B * HW2 * OMP);   // 9,216 u32
  u32* pco = pc1 + 9216;                             // 9,216 u32
  float* dcn   = x2;  // alias: x2 dead after dsta_safuse

  // pw1/pw2 in d_out scratch (consumed before dsta_out_m writes d_out).
  u32* pw1 = (u32*)d_out;              // 147,456 u32
  u32* pw2 = pw1 + 147456;             // 124,416 u32

  const size_t base_f32 = 10912128;
  const size_t need = base_f32 * 4ull + (size_t)B * HW2 * OMP * 2ull +
                      2ull * 9216 * 4ull;            // ~119.2 MB
  if (ws_size < need) {
    dsta_fill<<<fill_grid, 256, 0, stream>>>(
        out, out_size, 1.0e6f + (float)(ws_size >> 20));
    return;
  }

  dsta_pack<<<1134, 256, 0, stream>>>(mask1_w, mask2_w, conv1_w, out_w,
                                      pw1, pw2, pc1, pco);
  dsta_conv1_m<<<2304, 256, 0, stream>>>(x, (const uint4*)pc1, conv1_b, x2);
  dsta_stats<<<576, 256, 0, stream>>>(x2, stats);
  dsta_ca_red<<<128, 256, 0, stream>>>(x2, ap, mp);
  dsta_ca_mlp<<<1, 128, 0, stream>>>(ap, mp, ca_w1, ca_w2, sig);
  dsta_safuse<<<576, 256, 0, stream>>>(stats, x2, sig, sa_w, fuse_w, fuse_b,
                                       x2f);
  dsta_down<<<576, 256, 0, stream>>>(x2f, down_w, down_b, x3);
  dsta_om2_m<<<1152, 256, 0, stream>>>(x3, (const uint4*)pw2, mask2_b, om2r);
  dsta_dcn_m<<<2304, 256, 0, stream>>>(x2f, om2r, (const uint4*)pw1,
                                       mask1_b, dcn_w, dcn_b, dcn);
  dsta_out_m<<<2304, 256, 0, stream>>>(dcn, (const uint4*)pco, out_b, out);
}